// Round 1
// baseline (37.085 us; speedup 1.0000x reference)
//
#include <hip/hip_runtime.h>

// BSplineFFD2D: 4M points, each gathers a 4x4 float2 neighborhood from a
// 65x65x2 control grid (omega) and does a separable cubic-B-spline sum.
// omega is staged zero-padded in LDS (69x69 float2 = 38,088 B -> 4 blocks/CU).
//
// Reference quirk replicated deliberately: Bu (basis of u, from x) weights the
// ROW (y) offsets; Bv (from y) weights the COLUMN (x) offsets. Window offsets
// are arange(-2,2) = [-2..1], so in +2-padded coords the 4x4 window starts at
// exactly (iy, ix).

constexpr int kSX = 65;
constexpr int kSY = 65;
constexpr int kPC = 69;   // padded cols (row stride in LDS)
constexpr int kPR = 69;   // padded rows

__device__ __forceinline__ void bspline4(float u, float b[4]) {
    float u2 = u * u;
    float u3 = u2 * u;
    float om = 1.0f - u;
    b[0] = om * om * om * (1.0f / 6.0f);
    b[1] = (3.0f * u3 - 6.0f * u2 + 4.0f) * (1.0f / 6.0f);
    b[2] = (-3.0f * u3 + 3.0f * u2 + 3.0f * u + 1.0f) * (1.0f / 6.0f);
    b[3] = u3 * (1.0f / 6.0f);
}

__device__ __forceinline__ float2 eval_point(float gx, float gy,
                                             const float2* __restrict__ w) {
    // x = gx*512 + 512 ; exact power-of-two arithmetic matches jnp exactly
    float x = fmaf(gx, 512.0f, 512.0f);
    float y = fmaf(gy, 512.0f, 512.0f);
    float fx = floorf(x * 0.0625f);
    float fy = floorf(y * 0.0625f);
    int ix = (int)fx;
    int iy = (int)fy;
    float u = (x - fx * 16.0f) * 0.0625f;   // exact
    float v = (y - fy * 16.0f) * 0.0625f;   // exact

    // defensive clamp (no-op for the actual input range ix,iy in [32,63]);
    // keeps LDS indexing in-bounds for any input
    ix = max(0, min(ix, kSX));  // padded window rows/cols iy..iy+3 <= 68
    iy = max(0, min(iy, kSY));

    float bu[4], bv[4];
    bspline4(u, bu);
    bspline4(v, bv);

    const float2* base = w + iy * kPC + ix;
    float ax = 0.0f, ay = 0.0f;
#pragma unroll
    for (int i = 0; i < 4; ++i) {           // i: row offset (y), weighted by Bu
        const float2* row = base + i * kPC;
        float2 c0 = row[0];
        float2 c1 = row[1];
        float2 c2 = row[2];
        float2 c3 = row[3];
        float sx = fmaf(bv[0], c0.x, fmaf(bv[1], c1.x, fmaf(bv[2], c2.x, bv[3] * c3.x)));
        float sy = fmaf(bv[0], c0.y, fmaf(bv[1], c1.y, fmaf(bv[2], c2.y, bv[3] * c3.y)));
        ax = fmaf(bu[i], sx, ax);
        ay = fmaf(bu[i], sy, ay);
    }
    // disp * 2/1024 = disp / 512 (exact)
    return make_float2(ax * (1.0f / 512.0f), ay * (1.0f / 512.0f));
}

__global__ void __launch_bounds__(256)
bspline_ffd2d_kernel(const float* __restrict__ grid,
                     const float* __restrict__ omega,
                     float* __restrict__ out, int npts) {
    __shared__ float2 w[kPR * kPC];

    // zero-pad ring + interior (cheap: 4761 float2 per block)
    for (int i = threadIdx.x; i < kPR * kPC; i += blockDim.x)
        w[i] = make_float2(0.0f, 0.0f);
    __syncthreads();
    const float2* om2 = (const float2*)omega;
    for (int i = threadIdx.x; i < kSY * kSX; i += blockDim.x) {
        int r = i / kSX;
        int c = i - r * kSX;
        w[(r + 2) * kPC + (c + 2)] = om2[i];
    }
    __syncthreads();

    const float4* g4 = (const float4*)grid;  // 2 points per float4
    float4* o4 = (float4*)out;
    int npairs = npts >> 1;
    int stride = gridDim.x * blockDim.x;
    for (int p = blockIdx.x * blockDim.x + threadIdx.x; p < npairs; p += stride) {
        float4 g = g4[p];
        float2 r0 = eval_point(g.x, g.y, w);
        float2 r1 = eval_point(g.z, g.w, w);
        o4[p] = make_float4(r0.x, r0.y, r1.x, r1.y);
    }

    // odd-N tail (not hit for N=4M, kept for generality)
    if ((npts & 1) && blockIdx.x == 0 && threadIdx.x == 0) {
        int n = npts - 1;
        float2 g = ((const float2*)grid)[n];
        ((float2*)out)[n] = eval_point(g.x, g.y, w);
    }
}

extern "C" void kernel_launch(void* const* d_in, const int* in_sizes, int n_in,
                              void* d_out, int out_size, void* d_ws, size_t ws_size,
                              hipStream_t stream) {
    const float* grid = (const float*)d_in[0];    // (N,2) f32
    const float* omega = (const float*)d_in[1];   // (65,65,2) f32
    float* out = (float*)d_out;                   // (N,2) f32
    int npts = in_sizes[0] / 2;

    int npairs = npts >> 1;
    int blocks = (npairs + 255) / 256;
    if (blocks > 2048) blocks = 2048;
    if (blocks < 1) blocks = 1;
    bspline_ffd2d_kernel<<<dim3(blocks), dim3(256), 0, stream>>>(grid, omega, out, npts);
}

// Round 2
// 26.667 us; speedup vs baseline: 1.3907x; 1.3907x over previous
//
#include <hip/hip_runtime.h>
#include <hip/hip_fp16.h>

// BSplineFFD2D: 4M points, each gathers a 4x4 float2 neighborhood from a
// 65x65x2 control grid (omega) and does a separable cubic-B-spline sum.
//
// R2: omega staged in LDS as half2 (x,y packed, 4B per control point).
//  - LDS block 38.4KB -> 19KB: 8 blocks/CU (32 waves, was 16)
//  - LDS gather traffic 512MB -> 256MB, bank touches per point 32 -> 16
//  - fp16 quantization error bound: |dOmega| <= 3.9*2^-11 ~ 1.9e-3, basis
//    weights sum to 1 -> added output error <= 1.9e-3/512 = 3.7e-6,
//    far under the 6.65e-5 threshold (measured f32 absmax was 1.5e-5).
//
// Reference quirk replicated deliberately: Bu (basis of u, from x) weights the
// ROW (y) offsets; Bv (from y) weights the COLUMN (x) offsets. Window offsets
// are arange(-2,2) = [-2..1], so in +2-padded coords the 4x4 window starts at
// exactly (iy, ix).

constexpr int kSX = 65;
constexpr int kSY = 65;
constexpr int kPC = 69;   // padded cols (row stride in LDS, in half2 elems)
constexpr int kPR = 69;   // padded rows

__device__ __forceinline__ void bspline4(float u, float b[4]) {
    float u2 = u * u;
    float u3 = u2 * u;
    float om = 1.0f - u;
    b[0] = om * om * om * (1.0f / 6.0f);
    b[1] = (3.0f * u3 - 6.0f * u2 + 4.0f) * (1.0f / 6.0f);
    b[2] = (-3.0f * u3 + 3.0f * u2 + 3.0f * u + 1.0f) * (1.0f / 6.0f);
    b[3] = u3 * (1.0f / 6.0f);
}

__device__ __forceinline__ float2 eval_point(float gx, float gy,
                                             const __half2* __restrict__ w) {
    // x = gx*512 + 512 ; exact power-of-two arithmetic matches jnp exactly
    float x = fmaf(gx, 512.0f, 512.0f);
    float y = fmaf(gy, 512.0f, 512.0f);
    float fx = floorf(x * 0.0625f);
    float fy = floorf(y * 0.0625f);
    int ix = (int)fx;
    int iy = (int)fy;
    float u = (x - fx * 16.0f) * 0.0625f;   // exact
    float v = (y - fy * 16.0f) * 0.0625f;   // exact

    // defensive clamp (no-op for the actual input range ix,iy in [32,63]);
    // keeps LDS indexing in-bounds for any input
    ix = max(0, min(ix, kSX));  // window cols ix..ix+3 <= 68
    iy = max(0, min(iy, kSY));

    float bu[4], bv[4];
    bspline4(u, bu);
    bspline4(v, bv);

    const __half2* base = w + iy * kPC + ix;
    float ax = 0.0f, ay = 0.0f;
#pragma unroll
    for (int i = 0; i < 4; ++i) {           // i: row offset (y), weighted by Bu
        const __half2* row = base + i * kPC;
        float2 c0 = __half22float2(row[0]);
        float2 c1 = __half22float2(row[1]);
        float2 c2 = __half22float2(row[2]);
        float2 c3 = __half22float2(row[3]);
        float sx = fmaf(bv[0], c0.x, fmaf(bv[1], c1.x, fmaf(bv[2], c2.x, bv[3] * c3.x)));
        float sy = fmaf(bv[0], c0.y, fmaf(bv[1], c1.y, fmaf(bv[2], c2.y, bv[3] * c3.y)));
        ax = fmaf(bu[i], sx, ax);
        ay = fmaf(bu[i], sy, ay);
    }
    // disp * 2/1024 = disp / 512 (exact)
    return make_float2(ax * (1.0f / 512.0f), ay * (1.0f / 512.0f));
}

__global__ void __launch_bounds__(256, 8)
bspline_ffd2d_kernel(const float* __restrict__ grid,
                     const float* __restrict__ omega,
                     float* __restrict__ out, int npts) {
    __shared__ __half2 w[kPR * kPC];   // 19,044 B -> 8 blocks/CU

    // zero-pad ring + interior
    for (int i = threadIdx.x; i < kPR * kPC; i += blockDim.x)
        w[i] = __floats2half2_rn(0.0f, 0.0f);
    __syncthreads();
    const float2* om2 = (const float2*)omega;
    for (int i = threadIdx.x; i < kSY * kSX; i += blockDim.x) {
        int r = i / kSX;
        int c = i - r * kSX;
        float2 v = om2[i];
        w[(r + 2) * kPC + (c + 2)] = __floats2half2_rn(v.x, v.y);
    }
    __syncthreads();

    const float4* g4 = (const float4*)grid;  // 2 points per float4
    float4* o4 = (float4*)out;
    int npairs = npts >> 1;
    int stride = gridDim.x * blockDim.x;
    for (int p = blockIdx.x * blockDim.x + threadIdx.x; p < npairs; p += stride) {
        float4 g = g4[p];
        float2 r0 = eval_point(g.x, g.y, w);
        float2 r1 = eval_point(g.z, g.w, w);
        o4[p] = make_float4(r0.x, r0.y, r1.x, r1.y);
    }

    // odd-N tail (not hit for N=4M, kept for generality)
    if ((npts & 1) && blockIdx.x == 0 && threadIdx.x == 0) {
        int n = npts - 1;
        float2 g = ((const float2*)grid)[n];
        ((float2*)out)[n] = eval_point(g.x, g.y, w);
    }
}

extern "C" void kernel_launch(void* const* d_in, const int* in_sizes, int n_in,
                              void* d_out, int out_size, void* d_ws, size_t ws_size,
                              hipStream_t stream) {
    const float* grid = (const float*)d_in[0];    // (N,2) f32
    const float* omega = (const float*)d_in[1];   // (65,65,2) f32
    float* out = (float*)d_out;                   // (N,2) f32
    int npts = in_sizes[0] / 2;

    int npairs = npts >> 1;
    int blocks = (npairs + 255) / 256;
    if (blocks > 2048) blocks = 2048;
    if (blocks < 1) blocks = 1;
    bspline_ffd2d_kernel<<<dim3(blocks), dim3(256), 0, stream>>>(grid, omega, out, npts);
}